// Round 2
// baseline (398.803 us; speedup 1.0000x reference)
//
#include <hip/hip_runtime.h>
#include <hip/hip_bf16.h>

// HGNN_conv: the reference's floor(softmax/1000) term is identically zero
// (softmax in (0,1], /1000 < 1, floor -> 0), so e == G exactly and
//   out = G @ (x @ weight + bias).
// G has exactly K=5 ones per row at columns qq[5i..5i+4], so
//   out[i,f] = sum_k E[qq[5i+k], f] + 5*bias[f],  E = x @ weight.
//
// v2: gemm drops LDS staging entirely. Row indices are wave-uniform
// (forced via readfirstlane) so x loads compile to scalar s_load_dwordx4
// on the scalar pipe; the VALU does only the 32 FMAs/iter -> FMA-bound
// (~4096 cyc/wave). gather uses float4 lanes (16 lanes/row).

#define IN_FT 256
#define OUT_FT 64
#define KCARD 5
#define RPB 32   // rows of x per block (4 waves x 8 rows)

__global__ __launch_bounds__(256) void gemm_xw(const float* __restrict__ x,
                                               const float* __restrict__ w,
                                               float* __restrict__ e,
                                               int n2) {
    // wave-uniform row group; readfirstlane makes it provably uniform so
    // x loads scalarize to s_load_dwordx4 (scalar pipe, no VALU/LDS cost)
    const int wid = __builtin_amdgcn_readfirstlane(threadIdx.x >> 6);
    const int col = threadIdx.x & 63;
    const int r0  = blockIdx.x * RPB + wid * 8;

    // clamp OOB rows (uniform) to a harmless valid row; stores are guarded
    int ridx[8];
    #pragma unroll
    for (int rr = 0; rr < 8; ++rr) {
        int r = r0 + rr;
        ridx[rr] = (r < n2) ? r : (n2 - 1);
    }

    float acc[8] = {0.f, 0.f, 0.f, 0.f, 0.f, 0.f, 0.f, 0.f};

    for (int c = 0; c < IN_FT; c += 4) {
        // w reads: 64 lanes -> 256B coalesced, L2-hot after first block
        float w0 = w[(c + 0) * OUT_FT + col];
        float w1 = w[(c + 1) * OUT_FT + col];
        float w2 = w[(c + 2) * OUT_FT + col];
        float w3 = w[(c + 3) * OUT_FT + col];
        #pragma unroll
        for (int rr = 0; rr < 8; ++rr) {
            // uniform address -> s_load_dwordx4; SGPR operand in the FMA
            float4 xv = *(const float4*)(x + (size_t)ridx[rr] * IN_FT + c);
            acc[rr] = fmaf(xv.x, w0, acc[rr]);
            acc[rr] = fmaf(xv.y, w1, acc[rr]);
            acc[rr] = fmaf(xv.z, w2, acc[rr]);
            acc[rr] = fmaf(xv.w, w3, acc[rr]);
        }
    }

    #pragma unroll
    for (int rr = 0; rr < 8; ++rr) {
        int r = r0 + rr;
        if (r < n2) e[(size_t)r * OUT_FT + col] = acc[rr];
    }
}

__global__ __launch_bounds__(256) void gather_sum(const float* __restrict__ e,
                                                  const int* __restrict__ qq,
                                                  const float* __restrict__ bias,
                                                  float* __restrict__ out,
                                                  int n1) {
    const int t   = blockIdx.x * 256 + threadIdx.x;
    const int row = t >> 4;          // 16 lanes per output row (float4 each)
    const int f4  = t & 15;
    if (row >= n1) return;

    float4 bv = ((const float4*)bias)[f4];
    float4 s  = make_float4(bv.x * (float)KCARD, bv.y * (float)KCARD,
                            bv.z * (float)KCARD, bv.w * (float)KCARD);
    #pragma unroll
    for (int k = 0; k < KCARD; ++k) {
        int q = qq[row * KCARD + k];
        float4 ev = ((const float4*)(e + (size_t)q * OUT_FT))[f4];  // 256B/wave coalesced
        s.x += ev.x; s.y += ev.y; s.z += ev.z; s.w += ev.w;
    }
    ((float4*)(out + (size_t)row * OUT_FT))[f4] = s;
}

extern "C" void kernel_launch(void* const* d_in, const int* in_sizes, int n_in,
                              void* d_out, int out_size, void* d_ws, size_t ws_size,
                              hipStream_t stream) {
    // inputs: 0=x [N2*256], 1=G (unused), 2=weight [256*64], 3=a (unused),
    //         4=bias [64], 5=qq [N1*5], 6=rows (unused)
    const float* x    = (const float*)d_in[0];
    const float* w    = (const float*)d_in[2];
    const float* bias = (const float*)d_in[4];
    const int*   qq   = (const int*)d_in[5];
    float* out = (float*)d_out;
    float* e   = (float*)d_ws;               // [n2, OUT_FT] f32 scratch (2.56 MB)

    const int n2 = in_sizes[0] / IN_FT;      // 10000
    const int n1 = out_size / OUT_FT;        // 8192

    gemm_xw<<<dim3((n2 + RPB - 1) / RPB), 256, 0, stream>>>(x, w, e, n2);

    const int gthreads = n1 * (OUT_FT / 4);  // 16 lanes per row
    gather_sum<<<dim3((gthreads + 255) / 256), 256, 0, stream>>>(e, qq, bias, out, n1);
}